// Round 6
// baseline (153.538 us; speedup 1.0000x reference)
//
#include <hip/hip_runtime.h>
#include <hip/hip_bf16.h>

#define NN 8192
#define DD 128

typedef __attribute__((ext_vector_type(4))) float f32x4;
typedef __attribute__((ext_vector_type(8))) short bf16x8;

__device__ __forceinline__ short f2bf(float f) {
  __hip_bfloat16 h = __float2bfloat16(f);
  return __builtin_bit_cast(short, h);
}

// async global->LDS, 16B per lane. LDS dest = wave-uniform base + lane*16
// (linear); global src is per-lane (carries the swizzle).
__device__ __forceinline__ void async_copy16(void* lds, const void* g) {
  __builtin_amdgcn_global_load_lds(
      (const __attribute__((address_space(1))) void*)g,
      (__attribute__((address_space(3))) void*)lds, 16, 0, 0);
}

// ---------------------------------------------------------------------------
// Kernel 1: yT[n][k] = sum_d x[k][d] * W[d][n]   (bf16, transposed)
// W (64 KB) staged in LDS once; inner loop is LDS-only.
// ---------------------------------------------------------------------------
__global__ __launch_bounds__(256) void xw_kernel(
    const float* __restrict__ x, const float* __restrict__ W,
    short* __restrict__ yT)
{
  __shared__ float xs[32][129];
  __shared__ float Ws[128 * 128];
  const int t  = threadIdx.x;
  const int k0 = blockIdx.x * 32;

  #pragma unroll
  for (int i = 0; i < 16; ++i) {
    int idx = (i * 256 + t) * 4;
    *(f32x4*)&Ws[idx] = *(const f32x4*)(W + idx);
  }
  #pragma unroll
  for (int i = 0; i < 4; ++i) {
    int idx = i * 256 + t;
    int row = idx >> 5;
    int c4  = (idx & 31) * 4;
    f32x4 v = *(const f32x4*)(x + (size_t)(k0 + row) * DD + c4);
    xs[row][c4 + 0] = v[0]; xs[row][c4 + 1] = v[1];
    xs[row][c4 + 2] = v[2]; xs[row][c4 + 3] = v[3];
  }
  __syncthreads();

  const int kl = t & 31;
  const int g  = t >> 5;
  float acc[16];
  #pragma unroll
  for (int j = 0; j < 16; ++j) acc[j] = 0.f;

  for (int d = 0; d < 128; ++d) {
    float xv = xs[kl][d];
    const float* wr = &Ws[d * 128 + g * 16];
    f32x4 w0 = *(const f32x4*)(wr);
    f32x4 w1 = *(const f32x4*)(wr + 4);
    f32x4 w2 = *(const f32x4*)(wr + 8);
    f32x4 w3 = *(const f32x4*)(wr + 12);
    #pragma unroll
    for (int j = 0; j < 4; ++j) {
      acc[j]      += xv * w0[j];
      acc[4 + j]  += xv * w1[j];
      acc[8 + j]  += xv * w2[j];
      acc[12 + j] += xv * w3[j];
    }
  }
  #pragma unroll
  for (int j = 0; j < 16; ++j) {
    int n = g * 16 + j;
    yT[(size_t)n * NN + k0 + kl] = f2bf(acc[j]);
  }
}

// ---------------------------------------------------------------------------
// Kernel 2: partial[ks][m][n] = sum_{k in 2048-slice ks} A[m][k]*y[k][n]
//           degpart[ks][m]    = sum_{k in slice ks} A[m][k]
// 256 blocks = 64 row-groups x 4 k-slices; 1 block/CU resident.
// ks = b&3: XCD x (= b%8) always sees slice x&3 -> its 512KB Y slice stays
// L2-resident. Block: 512 thr / 8 waves; wave w owns rows w*16..w*16+15 --
// it stages ONLY those rows into LDS and reads ONLY those rows, so there
// are NO barriers: each wave runs a private 2-deep DMA pipeline paced by
// its own counted vmcnt. K-step = 128 floats -> every A row is fetched in
// 512-B contiguous runs (4x the previous run length; DRAM page friendly).
// Swizzle (rule 21): LDS linear dest; source 16B-group g of row r fetched
// as g^(r&7); reads XOR the same way -> conflict-free ds_read_b128.
// Y (L2-resident) is read straight to registers, no LDS.
// ---------------------------------------------------------------------------
__global__ __launch_bounds__(512, 2) void gcn_main(
    const float* __restrict__ A, const short* __restrict__ yT,
    float* __restrict__ part, float* __restrict__ degpart)
{
  __shared__ float Abuf[2][128 * 128];   // 2 x 64 KB

  const int tid   = threadIdx.x;
  const int l     = tid & 63;
  const int w     = tid >> 6;            // wave 0..7
  const int ks    = blockIdx.x & 3;      // k-slice; XCD x -> ks = x&3
  const int mg    = blockIdx.x >> 2;     // 0..63
  const int R0    = mg * 128;
  const int kbase = ks * 2048;
  const int l15   = l & 15;
  const int kg    = l >> 4;              // 0..3

  // --- staging lane constants: instr j covers rows w*16+2j (+sh) ---
  const int sh   = l >> 5;               // 0/1: row within pair
  const int sgrp = l & 31;               // 16B group position within row
  const float* gA[8];
  #pragma unroll
  for (int j = 0; j < 8; ++j) {
    const int r = w * 16 + 2 * j + sh;
    // fetched global group = sgrp ^ (r&7); (2j+sh)&7 == ((2j)&7)|sh (no carry)
    gA[j] = A + (size_t)(R0 + r) * NN + kbase
              + ((sgrp ^ ((2 * j) & 7) ^ sh) << 2);
  }

  // --- read-side constants ---
  const int arow   = w * 16 + l15;       // this lane's A row (wave-local set)
  const int axor   = arow & 7;
  const int arow_l = arow * 128;         // float offset of row base in tile
  const short* yrow = yT + (size_t)l15 * NN + kg * 8;

  f32x4 acc[8];
  #pragma unroll
  for (int n = 0; n < 8; ++n) acc[n] = (f32x4)0.f;
  float deg = 0.f;

#define STAGE(buf, step) do {                                              \
    _Pragma("unroll")                                                      \
    for (int j = 0; j < 8; ++j)                                            \
      async_copy16(&Abuf[buf][(w * 16 + 2 * j) * 128],                     \
                   gA[j] + (step) * 128);                                  \
  } while (0)

  // prologue: 2-deep pipe (16 x 1KB DMA in flight per wave)
  STAGE(0, 0);
  STAGE(1, 1);

  for (int s = 0; s < 16; ++s) {
    __builtin_amdgcn_sched_barrier(0);
    if (s < 15) asm volatile("s_waitcnt vmcnt(8)" ::: "memory");
    else        asm volatile("s_waitcnt vmcnt(0)" ::: "memory");
    __builtin_amdgcn_sched_barrier(0);

    const float* Ab = &Abuf[s & 1][0];
    const int koff  = kbase + s * 128;
    #pragma unroll
    for (int ss = 0; ss < 4; ++ss) {
      const int g0 = ss * 8 + kg * 2;
      f32x4 alo = *(const f32x4*)&Ab[arow_l + (((g0    ) ^ axor) << 2)];
      f32x4 ahi = *(const f32x4*)&Ab[arow_l + (((g0 + 1) ^ axor) << 2)];

      deg += (alo[0] + alo[1]) + (alo[2] + alo[3])
           + (ahi[0] + ahi[1]) + (ahi[2] + ahi[3]);

      bf16x8 a;
      #pragma unroll
      for (int j = 0; j < 4; ++j) {
        a[j]     = f2bf(alo[j]);
        a[4 + j] = f2bf(ahi[j]);
      }

      #pragma unroll
      for (int n = 0; n < 8; ++n) {
        bf16x8 b = *(const bf16x8*)(yrow + (size_t)(n * 16) * NN
                                         + koff + ss * 32);
        acc[n] = __builtin_amdgcn_mfma_f32_16x16x32_bf16(a, b, acc[n], 0, 0, 0);
      }
    }

    __builtin_amdgcn_sched_barrier(0);
    if (s + 2 < 16) STAGE(s & 1, s + 2);
  }
#undef STAGE

  // --- degree: sum the 4 kg lane-groups (same l15 = same row) ---
  deg += __shfl_xor(deg, 16);
  deg += __shfl_xor(deg, 32);
  if (l < 16)
    degpart[(size_t)ks * NN + R0 + w * 16 + l] = deg;

  // --- partial C tile -> d_ws ---
  float* pbase = part + (size_t)ks * NN * DD + (size_t)(R0 + w * 16) * DD;
  #pragma unroll
  for (int n = 0; n < 8; ++n)
    #pragma unroll
    for (int i = 0; i < 4; ++i)
      __builtin_nontemporal_store(acc[n][i],
          pbase + (size_t)(kg * 4 + i) * DD + n * 16 + l15);
}

// ---------------------------------------------------------------------------
// Kernel 3: out[m][n] = (sum_ks part[ks][m][n]) / (sum_ks degpart[ks][m])
// ---------------------------------------------------------------------------
__global__ __launch_bounds__(256) void reduce_kernel(
    const float* __restrict__ part, const float* __restrict__ degpart,
    float* __restrict__ out)
{
  const int idx = blockIdx.x * 256 + threadIdx.x;   // 0 .. 8192*32-1
  const int m   = idx >> 5;
  const int c4  = (idx & 31) * 4;

  f32x4 s = (f32x4)0.f;
  float d = 0.f;
  #pragma unroll
  for (int ks = 0; ks < 4; ++ks) {
    f32x4 v = *(const f32x4*)(part + (size_t)ks * NN * DD + (size_t)m * DD + c4);
    s[0] += v[0]; s[1] += v[1]; s[2] += v[2]; s[3] += v[3];
    d += degpart[(size_t)ks * NN + m];
  }
  f32x4 r;
  r[0] = s[0] / d; r[1] = s[1] / d; r[2] = s[2] / d; r[3] = s[3] / d;
  *(f32x4*)(out + (size_t)m * DD + c4) = r;
}

extern "C" void kernel_launch(void* const* d_in, const int* in_sizes, int n_in,
                              void* d_out, int out_size, void* d_ws, size_t ws_size,
                              hipStream_t stream) {
  const float* x = (const float*)d_in[0];   // [8192,128] fp32
  const float* A = (const float*)d_in[1];   // [8192,8192] fp32
  const float* W = (const float*)d_in[2];   // [128,128] fp32
  float* out = (float*)d_out;               // [8192,128] fp32

  // workspace layout
  char* ws = (char*)d_ws;
  short* yT      = (short*)ws;                              // 2 MB  bf16 [128][8192]
  float* part    = (float*)(ws + (2u << 20));               // 16 MB fp32 [4][8192][128]
  float* degpart = (float*)(ws + (2u << 20) + (16u << 20)); // 128 KB fp32 [4][8192]

  xw_kernel<<<256, 256, 0, stream>>>(x, W, yT);
  gcn_main<<<256, 512, 0, stream>>>(A, yT, part, degpart);
  reduce_kernel<<<1024, 256, 0, stream>>>(part, degpart, out);
}